// Round 11
// baseline (899.745 us; speedup 1.0000x reference)
//
#include <hip/hip_runtime.h>
#include <hip/hip_bf16.h>
#include <cstdint>

// QuantizedLinear: Y[M,N] = X[M,K] . W^T + bias.  M=8192, N=16384, K=4096.
// INT8 path: W -> i8 exact; X -> per-row absmax i8 + row-sum (exact zp corr).
// GEMM mfma_i32_16x16x64_i8.  R11: 2 independent blocks/CU (m97/m114 cross-
// block overlap) with the R9 wave-tile ratio kept:
//   block 256x128, 256 threads (4 waves, 2x2), wave tile 128x64 (8m x 4n),
//   BK=64, LDS 48KB dbuf, regs ~190 <= 256 -> 2 blocks/CU.
// 2-phase schedule per K-tile (R8 staging rule + R10 lesson: cross-wave
// staged data is read only AFTER the barrier following its vmcnt):
//   P1: read all 12 frags(t) from cb; stage B(t+1)->nb; lgkm(2); Q(n0-1); bar
//   P2: stage A(t+2)->cb; lgkm(0); Q(n2-3); vmcnt(4) [=tile t+1 landed]; bar
// T2 xor-swizzle for 64B rows (slot = kq ^ ((fr>>1)&3), verified 8 lanes per
// 4-bank group -> 0 conflicts), T5 setprio, col-major-per-XCD grid.

#define M_DIM 8192
#define N_DIM 16384
#define K_DIM 4096
#define BK    64
#define NT    (K_DIM / BK)   // 64 k-tiles

using i32x4 = __attribute__((ext_vector_type(4))) int;

// ---------------- prepass: X -> i8 per-row absmax ----------------
__global__ __launch_bounds__(256) void quant_x_kernel(const float* __restrict__ x,
                                                      signed char* __restrict__ xq,
                                                      float* __restrict__ rs1,
                                                      float* __restrict__ rs2) {
    const int row = blockIdx.x;
    const float* xr = x + (size_t)row * K_DIM;
    const int tid = threadIdx.x;

    float4 v[4];
    float amax = 0.f;
    #pragma unroll
    for (int j = 0; j < 4; ++j) {
        v[j] = *(const float4*)(xr + j * 1024 + tid * 4);
        amax = fmaxf(amax, fmaxf(fmaxf(fabsf(v[j].x), fabsf(v[j].y)),
                                 fmaxf(fabsf(v[j].z), fabsf(v[j].w))));
    }
    #pragma unroll
    for (int off = 32; off > 0; off >>= 1)
        amax = fmaxf(amax, __shfl_xor(amax, off));
    __shared__ float smax[4];
    __shared__ int   ssum[4];
    const int wv = tid >> 6, ln = tid & 63;
    if (ln == 0) smax[wv] = amax;
    __syncthreads();
    amax = fmaxf(fmaxf(smax[0], smax[1]), fmaxf(smax[2], smax[3]));
    const float s   = amax * (1.0f / 127.0f);
    const float inv = amax > 0.f ? 127.0f / amax : 0.f;

    int sum = 0;
    #pragma unroll
    for (int j = 0; j < 4; ++j) {
        int q0 = (int)__builtin_rintf(v[j].x * inv);
        int q1 = (int)__builtin_rintf(v[j].y * inv);
        int q2 = (int)__builtin_rintf(v[j].z * inv);
        int q3 = (int)__builtin_rintf(v[j].w * inv);
        sum += q0 + q1 + q2 + q3;
        int packed = (q0 & 255) | ((q1 & 255) << 8) | ((q2 & 255) << 16) | ((q3 & 255) << 24);
        *(int*)(xq + (size_t)row * K_DIM + j * 1024 + tid * 4) = packed;
    }
    #pragma unroll
    for (int off = 32; off > 0; off >>= 1)
        sum += __shfl_xor(sum, off);
    if (ln == 0) ssum[wv] = sum;
    __syncthreads();
    if (tid == 0) {
        int t = ssum[0] + ssum[1] + ssum[2] + ssum[3];
        rs1[row] = s;
        rs2[row] = s * (float)t;
    }
}

// ---------------- prepass: W int32 -> i8 (exact) ----------------
__global__ void quant_w_kernel(const int* __restrict__ q, signed char* __restrict__ o,
                               long long n) {
    long long i = ((long long)blockIdx.x * blockDim.x + threadIdx.x) * 4;
    const long long stride = (long long)gridDim.x * blockDim.x * 4;
    for (; i < n; i += stride) {
        int4 v = *(const int4*)(q + i);
        int packed = (v.x & 255) | ((v.y & 255) << 8) | ((v.z & 255) << 16) | ((v.w & 255) << 24);
        *(int*)(o + i) = packed;
    }
}

// ---------------- GEMM ----------------
#define SB() __builtin_amdgcn_sched_barrier(0)

__device__ __forceinline__ void barrier_() {
    SB();
    asm volatile("" ::: "memory");
    __builtin_amdgcn_s_barrier();
    asm volatile("" ::: "memory");
    SB();
}

// With 256 threads: one gload_lds instr covers 64 rows x 64 B (4 KiB);
// thread t -> row t>>2, slot (t&3)^((t>>3)&3)  [inverse of the read swizzle].
// l0 = region + wave*1024 (wave-uniform); lanes write lane*16B.
__device__ __forceinline__ void stage_A4(const signed char* g0, unsigned char* l0) {
    #pragma unroll
    for (int j = 0; j < 4; ++j)
        __builtin_amdgcn_global_load_lds(
            (const __attribute__((address_space(1))) void*)(g0 + (size_t)(j * 64) * K_DIM),
            (__attribute__((address_space(3))) void*)(l0 + j * 4096), 16, 0, 0);
}
__device__ __forceinline__ void stage_B2(const signed char* g0, unsigned char* l0) {
    #pragma unroll
    for (int j = 0; j < 2; ++j)
        __builtin_amdgcn_global_load_lds(
            (const __attribute__((address_space(1))) void*)(g0 + (size_t)(j * 64) * K_DIM),
            (__attribute__((address_space(3))) void*)(l0 + j * 4096), 16, 0, 0);
}

__global__ __launch_bounds__(256, 2) void gemm_i8_kernel(const signed char* __restrict__ A,
                                                         const signed char* __restrict__ B,
                                                         const float* __restrict__ rs1,
                                                         const float* __restrict__ rs2,
                                                         const float* __restrict__ scale,
                                                         const float* __restrict__ zpp,
                                                         const float* __restrict__ bias,
                                                         float* __restrict__ C) {
    extern __shared__ unsigned char smem[];   // 48 KiB: 2 bufs x (A 16K + B 8K)

    const int tid  = threadIdx.x;
    const int wave = tid >> 6;
    const int lane = tid & 63;
    const int fr = lane & 15, kq = lane >> 4;   // 16x16 frag: row/col = fr, k-slot = kq
    const int wr = wave >> 1, wc = wave & 1;    // wave tile 128x64 in 2x2 grid

    // Bijective XCD swizzle (nwg = 4096); col-major within each XCD chunk:
    // 32 consecutive blocks share one 512KB B panel (L2-resident).
    const int swz = (blockIdx.x & 7) * 512 + (blockIdx.x >> 3);
    const int tileRow = (swz & 31) * 256;
    const int tileCol = (swz >> 5) * 128;

    // ---- staging addressing: row = tid>>2, slot = (tid&3)^((tid>>3)&3) ----
    const size_t goff = (size_t)(tid >> 2) * K_DIM + (((tid & 3) ^ ((tid >> 3) & 3)) * 16);
    const signed char* Au = A + (size_t)tileRow * K_DIM + goff;
    const signed char* Bu = B + (size_t)tileCol * K_DIM + goff;

    // ---- read addressing (swizzled), byte offsets ----
    const int cs   = (kq ^ ((fr >> 1) & 3)) * 16;
    const int aoff = wr * 8192 + fr * 64 + cs;            // + m*1024, m=0..7
    const int boff = 16384 + wc * 4096 + fr * 64 + cs;    // + n*1024, n=0..3

    i32x4 acc[8][4] = {};
    i32x4 arA[8], b0r[2], b1r[2];

    // ---- prologue: stage A(0) [4], B(0) [2], A(1) [4]; vmcnt(4) -> t0 landed ----
    {
        unsigned char* w0 = smem + wave * 1024;
        unsigned char* w1 = smem + 24576 + wave * 1024;
        stage_A4(Au,      w0);          // A(0)
        stage_B2(Bu,      w0 + 16384);  // B(0)
        stage_A4(Au + BK, w1);          // A(1)
    }
    SB();
    asm volatile("s_waitcnt vmcnt(4)" ::: "memory");   // tile0 (6 oldest) landed
    barrier_();

    for (int t = 0; t < NT; ++t) {
        const unsigned char* cb = smem + (t & 1) * 24576;
        unsigned char* cw = smem + (t & 1) * 24576 + wave * 1024;
        unsigned char* nw = smem + ((t + 1) & 1) * 24576 + wave * 1024;

        // ===== P1: read all frags(t) from cb [post-barrier: cross-wave safe];
        //           stage B(t+1)->nb; lgkm(2)[arA,b0r ready]; Q(n0-1); bar =====
        #pragma unroll
        for (int m = 0; m < 8; ++m)
            arA[m] = *(const i32x4*)(cb + aoff + m * 1024);
        #pragma unroll
        for (int n = 0; n < 2; ++n)
            b0r[n] = *(const i32x4*)(cb + boff + n * 1024);
        SB();   // pin order: b1r issued after arA/b0r
        #pragma unroll
        for (int n = 0; n < 2; ++n)
            b1r[n] = *(const i32x4*)(cb + boff + (n + 2) * 1024);
        SB();
        if (t + 1 < NT) stage_B2(Bu + (t + 1) * BK, nw + 16384);
        SB();
        asm volatile("s_waitcnt lgkmcnt(2)" ::: "memory");
        SB();
        __builtin_amdgcn_s_setprio(1);
        #pragma unroll
        for (int m = 0; m < 8; ++m)
            #pragma unroll
            for (int n = 0; n < 2; ++n)
                acc[m][n] = __builtin_amdgcn_mfma_i32_16x16x64_i8(arA[m], b0r[n], acc[m][n], 0, 0, 0);
        __builtin_amdgcn_s_setprio(0);
        barrier_();   // licenses P2's staging of A(t+2) over A(t)

        // ===== P2: stage A(t+2)->cb [A(t) readers retired + barrier];
        //           lgkm(0)[b1r ready]; Q(n2-3); vmcnt(4); bar =====
        if (t + 2 < NT) stage_A4(Au + (t + 2) * BK, cw);
        SB();
        asm volatile("s_waitcnt lgkmcnt(0)" ::: "memory");
        SB();
        __builtin_amdgcn_s_setprio(1);
        #pragma unroll
        for (int m = 0; m < 8; ++m)
            #pragma unroll
            for (int n = 0; n < 2; ++n)
                acc[m][n + 2] = __builtin_amdgcn_mfma_i32_16x16x64_i8(arA[m], b1r[n], acc[m][n + 2], 0, 0, 0);
        __builtin_amdgcn_s_setprio(0);
        SB();
        if (t + 2 < NT) {
            // queue: A(t+1)x4, B(t+1)x2, A(t+2)x4 -> retire 6 oldest = tile t+1
            asm volatile("s_waitcnt vmcnt(4)" ::: "memory");
        } else if (t + 1 < NT) {
            asm volatile("s_waitcnt vmcnt(0)" ::: "memory");   // tail drain
        }
        barrier_();   // makes tile t+1 visible to ALL waves before P1(t+1) reads
    }

    // ---- epilogue: 16x16 C/D layout col = lane&15, row = kq*4 + j ----
    const float sw  = scale[0];
    const float zpv = zpp[0];
    float bv[4];
    #pragma unroll
    for (int n = 0; n < 4; ++n)
        bv[n] = bias[tileCol + wc * 64 + n * 16 + fr];
    #pragma unroll
    for (int m = 0; m < 8; ++m) {
        #pragma unroll
        for (int j = 0; j < 4; ++j) {
            const int grow = tileRow + wr * 128 + m * 16 + kq * 4 + j;
            const float f1 = rs1[grow] * sw;
            const float f2 = zpv * rs2[grow] * sw;
            float* Crow = C + (size_t)grow * N_DIM + tileCol + wc * 64 + fr;
            #pragma unroll
            for (int n = 0; n < 4; ++n)
                Crow[n * 16] = f1 * (float)acc[m][n][j] - f2 + bv[n];
        }
    }
}

// Fallback (only if ws too small): basic LDS-tiled f32 GEMM.
__global__ void gemm_naive(const float* __restrict__ x, const int* __restrict__ wq,
                           const float* __restrict__ sp, const float* __restrict__ zp,
                           const float* __restrict__ bias, float* __restrict__ out) {
    __shared__ float sX[32][33];
    __shared__ float sW[32][33];
    const float s = sp[0], z = zp[0];
    const int tx = threadIdx.x & 15, ty = threadIdx.x >> 4;
    const int row0 = blockIdx.y * 32, col0 = blockIdx.x * 32;
    float acc[2][2] = {};
    for (int k0 = 0; k0 < K_DIM; k0 += 32) {
        for (int i = threadIdx.x; i < 32 * 32; i += 256) {
            int r = i >> 5, cc2 = i & 31;
            sX[r][cc2] = x[(size_t)(row0 + r) * K_DIM + k0 + cc2];
            sW[r][cc2] = ((float)wq[(size_t)(col0 + r) * K_DIM + k0 + cc2] - z) * s;
        }
        __syncthreads();
        #pragma unroll
        for (int k = 0; k < 32; ++k) {
            float xa0 = sX[ty * 2][k], xa1 = sX[ty * 2 + 1][k];
            float wb0 = sW[tx * 2][k], wb1 = sW[tx * 2 + 1][k];
            acc[0][0] += xa0 * wb0; acc[0][1] += xa0 * wb1;
            acc[1][0] += xa1 * wb0; acc[1][1] += xa1 * wb1;
        }
        __syncthreads();
    }
    #pragma unroll
    for (int i = 0; i < 2; ++i)
        #pragma unroll
        for (int j = 0; j < 2; ++j)
            out[(size_t)(row0 + ty * 2 + i) * N_DIM + (col0 + tx * 2 + j)] =
                acc[i][j] + bias[col0 + tx * 2 + j];
}

extern "C" void kernel_launch(void* const* d_in, const int* in_sizes, int n_in,
                              void* d_out, int out_size, void* d_ws, size_t ws_size,
                              hipStream_t stream) {
    const float* x     = (const float*)d_in[0];
    const int*   wq    = (const int*)d_in[1];
    const float* scale = (const float*)d_in[2];
    const float* zp    = (const float*)d_in[3];
    const float* bias  = (const float*)d_in[4];
    float* out = (float*)d_out;

    // ws layout: xq (32Mi) | wq8 (64Mi) | rs1 | rs2
    const size_t offXq = 0;
    const size_t offWq = (size_t)M_DIM * K_DIM;
    const size_t offR1 = offWq + (size_t)N_DIM * K_DIM;
    const size_t offR2 = offR1 + (size_t)M_DIM * sizeof(float);
    const size_t need  = offR2 + (size_t)M_DIM * sizeof(float);

    if (ws_size >= need) {
        signed char* xq  = (signed char*)d_ws + offXq;
        signed char* wq8 = (signed char*)d_ws + offWq;
        float* rs1 = (float*)((char*)d_ws + offR1);
        float* rs2 = (float*)((char*)d_ws + offR2);
        quant_x_kernel<<<M_DIM, 256, 0, stream>>>(x, xq, rs1, rs2);
        quant_w_kernel<<<4096, 256, 0, stream>>>(wq, wq8, (long long)N_DIM * K_DIM);
        (void)hipFuncSetAttribute((const void*)gemm_i8_kernel,
                                  hipFuncAttributeMaxDynamicSharedMemorySize, 49152);
        gemm_i8_kernel<<<(M_DIM / 256) * (N_DIM / 128), 256, 49152, stream>>>(
            xq, wq8, rs1, rs2, scale, zp, bias, out);
    } else {
        dim3 grid(N_DIM / 32, M_DIM / 32);
        gemm_naive<<<grid, 256, 0, stream>>>(x, wq, scale, zp, bias, out);
    }
}

// Round 14
// 681.771 us; speedup vs baseline: 1.3197x; 1.3197x over previous
//
#include <hip/hip_runtime.h>
#include <hip/hip_bf16.h>
#include <cstdint>

// QuantizedLinear: Y[M,N] = X[M,K] . W^T + bias.  M=8192, N=16384, K=4096.
// INT8 path: W -> i8 exact; X -> per-row absmax i8 + row-sum (exact zp corr).
// GEMM mfma_i32_16x16x64_i8, 256x256 tile, BK=128, 8 waves (2x4), 128KiB LDS
// dbuf.  R14 = R13's m201-style 8-phase interleave with the staging race
// FIXED.  Region last-reader table (per phase, trailing barrier = license):
//   Ah0: arA(kh) p0/p4, arB(kh) p2/p6 (wr=0 waves)  -> last p6 -> stage p7
//   Ah1: same phases (wr=1 waves)                    -> last p6 -> stage p7
//   Bh0: b0 p0/p4, b1 p1/p5 (wc=0,1)                 -> last p5 -> stage p6
//   Bh1: same (wc=2,3)                               -> last p5 -> stage p6
// (R13 staged Ah0 at p5 — before its p6 reader. That was the race.)
// Counted vmcnt(8) at p7: queue [t+1: B,B,A,A][t+2: B,B,A,A] (2 gloads each)
// -> retires exactly tile t+1; vmcnt(0) only at t=NT-2.  Prologue stages t1
// as B,B,A,A to match.  Explicit lgkm(0) per read-phase (R12 lesson).
// T2 xor-swizzle (0 conflicts), T5 setprio, XCD-swizzled grid.

#define M_DIM 8192
#define N_DIM 16384
#define K_DIM 4096
#define BK    128
#define NT    (K_DIM / BK)   // 32 k-tiles

using i32x4 = __attribute__((ext_vector_type(4))) int;

// ---------------- prepass: X -> i8 per-row absmax ----------------
__global__ __launch_bounds__(256) void quant_x_kernel(const float* __restrict__ x,
                                                      signed char* __restrict__ xq,
                                                      float* __restrict__ rs1,
                                                      float* __restrict__ rs2) {
    const int row = blockIdx.x;
    const float* xr = x + (size_t)row * K_DIM;
    const int tid = threadIdx.x;

    float4 v[4];
    float amax = 0.f;
    #pragma unroll
    for (int j = 0; j < 4; ++j) {
        v[j] = *(const float4*)(xr + j * 1024 + tid * 4);
        amax = fmaxf(amax, fmaxf(fmaxf(fabsf(v[j].x), fabsf(v[j].y)),
                                 fmaxf(fabsf(v[j].z), fabsf(v[j].w))));
    }
    #pragma unroll
    for (int off = 32; off > 0; off >>= 1)
        amax = fmaxf(amax, __shfl_xor(amax, off));
    __shared__ float smax[4];
    __shared__ int   ssum[4];
    const int wv = tid >> 6, ln = tid & 63;
    if (ln == 0) smax[wv] = amax;
    __syncthreads();
    amax = fmaxf(fmaxf(smax[0], smax[1]), fmaxf(smax[2], smax[3]));
    const float s   = amax * (1.0f / 127.0f);
    const float inv = amax > 0.f ? 127.0f / amax : 0.f;

    int sum = 0;
    #pragma unroll
    for (int j = 0; j < 4; ++j) {
        int q0 = (int)__builtin_rintf(v[j].x * inv);
        int q1 = (int)__builtin_rintf(v[j].y * inv);
        int q2 = (int)__builtin_rintf(v[j].z * inv);
        int q3 = (int)__builtin_rintf(v[j].w * inv);
        sum += q0 + q1 + q2 + q3;
        int packed = (q0 & 255) | ((q1 & 255) << 8) | ((q2 & 255) << 16) | ((q3 & 255) << 24);
        *(int*)(xq + (size_t)row * K_DIM + j * 1024 + tid * 4) = packed;
    }
    #pragma unroll
    for (int off = 32; off > 0; off >>= 1)
        sum += __shfl_xor(sum, off);
    if (ln == 0) ssum[wv] = sum;
    __syncthreads();
    if (tid == 0) {
        int t = ssum[0] + ssum[1] + ssum[2] + ssum[3];
        rs1[row] = s;
        rs2[row] = s * (float)t;
    }
}

// ---------------- prepass: W int32 -> i8 (exact) ----------------
__global__ void quant_w_kernel(const int* __restrict__ q, signed char* __restrict__ o,
                               long long n) {
    long long i = ((long long)blockIdx.x * blockDim.x + threadIdx.x) * 4;
    const long long stride = (long long)gridDim.x * blockDim.x * 4;
    for (; i < n; i += stride) {
        int4 v = *(const int4*)(q + i);
        int packed = (v.x & 255) | ((v.y & 255) << 8) | ((v.z & 255) << 16) | ((v.w & 255) << 24);
        *(int*)(o + i) = packed;
    }
}

// ---------------- GEMM ----------------
#define SB() __builtin_amdgcn_sched_barrier(0)

__device__ __forceinline__ void barrier_() {
    SB();
    asm volatile("" ::: "memory");
    __builtin_amdgcn_s_barrier();
    asm volatile("" ::: "memory");
    SB();
}

// Stage one 128-row x 128-byte half-tile (16 KiB) with 512 threads:
// 2 gload_lds w16; instr j covers rows j*64 + tid>>3.
// LDS[r][c16] = G[r][c16 ^ (r&7)] via inverse-swizzled global source.
__device__ __forceinline__ void stage_half(const signed char* g0, unsigned char* l0) {
    __builtin_amdgcn_global_load_lds((const __attribute__((address_space(1))) void*)g0,
                                     (__attribute__((address_space(3))) void*)l0, 16, 0, 0);
    __builtin_amdgcn_global_load_lds(
        (const __attribute__((address_space(1))) void*)(g0 + (size_t)64 * K_DIM),
        (__attribute__((address_space(3))) void*)(l0 + 8192), 16, 0, 0);
}

__global__ __launch_bounds__(512, 2) void gemm_i8_kernel(const signed char* __restrict__ A,
                                                         const signed char* __restrict__ B,
                                                         const float* __restrict__ rs1,
                                                         const float* __restrict__ rs2,
                                                         const float* __restrict__ scale,
                                                         const float* __restrict__ zpp,
                                                         const float* __restrict__ bias,
                                                         float* __restrict__ C) {
    extern __shared__ unsigned char smem[];   // 128 KiB: 2 bufs x (A 32K + B 32K)

    const int tid  = threadIdx.x;
    const int wave = tid >> 6;
    const int lane = tid & 63;
    const int fr = lane & 15, kq = lane >> 4;      // 16x16 frag: row/col=fr, k-slot=kq
    const int wr = wave >> 2, wc = wave & 3;       // wave tile 128x64 in 2x4 grid

    // XCD-aware bijective swizzle: nwg = 2048, divisible by 8.
    const int swz = (blockIdx.x & 7) * 256 + (blockIdx.x >> 3);
    const int ntn = N_DIM / 256;
    const int tileRow = (swz / ntn) * 256;
    const int tileCol = (swz % ntn) * 256;

    // ---- staging addressing (bytes) ----
    const size_t goff = (size_t)(tid >> 3) * K_DIM + (((tid & 7) ^ ((tid >> 3) & 7)) * 16);
    const signed char* Au  = A + (size_t)tileRow * K_DIM + goff;
    const signed char* Bu  = B + (size_t)tileCol * K_DIM + goff;
    const signed char* AuH = Au + (size_t)128 * K_DIM;
    const signed char* BuH = Bu + (size_t)128 * K_DIM;

    // ---- read addressing (swizzled), byte offsets ----
    const int aoffB = wr * 16384 + fr * 128;            // + m*2048 + cs[kh]
    const int boffB = 32768 + wc * 8192 + fr * 128;     // + n*2048 + cs[kh]
    int cs[2];
    #pragma unroll
    for (int kh = 0; kh < 2; ++kh)
        cs[kh] = ((kh * 4 + kq) ^ (fr & 7)) * 16;

    i32x4 acc[8][4] = {};
    i32x4 arA[4], arB[4], b0[2], b1[2];

    // ---- prologue: stage t0 (8 halves) + t1 (B,B,A,A); vmcnt(8); bar ----
    {
        unsigned char* w0 = smem + wave * 1024;
        unsigned char* w1 = smem + 65536 + wave * 1024;
        stage_half(Au,  w0);                // t0 Ah0
        stage_half(AuH, w0 + 16384);        // t0 Ah1
        stage_half(Bu,  w0 + 32768);        // t0 Bh0
        stage_half(BuH, w0 + 49152);        // t0 Bh1
        stage_half(Bu + BK,  w1 + 32768);   // t1 Bh0
        stage_half(BuH + BK, w1 + 49152);   // t1 Bh1
        stage_half(Au + BK,  w1);           // t1 Ah0
        stage_half(AuH + BK, w1 + 16384);   // t1 Ah1
    }
    SB();
    asm volatile("s_waitcnt vmcnt(8)" ::: "memory");   // tile0 landed
    barrier_();

    for (int t = 0; t < NT; ++t) {
        const unsigned char* cb = smem + (t & 1) * 65536;
        unsigned char* sw = smem + (t & 1) * 65536 + wave * 1024;   // t+2 dest
        const int kn2 = (t + 2) * BK;
        const bool st = (t + 2 < NT);

        #pragma unroll
        for (int kh = 0; kh < 2; ++kh) {
            const int c = cs[kh];

            // ===== phase A (p0/p4): read arA(kh)+b0(kh); bar; lgkm0; Q00 =====
            #pragma unroll
            for (int m = 0; m < 4; ++m)
                arA[m] = *(const i32x4*)(cb + aoffB + m * 2048 + c);
            #pragma unroll
            for (int n = 0; n < 2; ++n)
                b0[n] = *(const i32x4*)(cb + boffB + n * 2048 + c);
            barrier_();
            asm volatile("s_waitcnt lgkmcnt(0)" ::: "memory");
            SB();
            __builtin_amdgcn_s_setprio(1);
            #pragma unroll
            for (int m = 0; m < 4; ++m)
                #pragma unroll
                for (int n = 0; n < 2; ++n)
                    acc[m][n] = __builtin_amdgcn_mfma_i32_16x16x64_i8(arA[m], b0[n], acc[m][n], 0, 0, 0);
            __builtin_amdgcn_s_setprio(0);
            barrier_();

            // ===== phase B (p1/p5): read b1(kh); bar; lgkm0; Q01 =====
            #pragma unroll
            for (int n = 0; n < 2; ++n)
                b1[n] = *(const i32x4*)(cb + boffB + (n + 2) * 2048 + c);
            barrier_();
            asm volatile("s_waitcnt lgkmcnt(0)" ::: "memory");
            SB();
            __builtin_amdgcn_s_setprio(1);
            #pragma unroll
            for (int m = 0; m < 4; ++m)
                #pragma unroll
                for (int n = 0; n < 2; ++n)
                    acc[m][n + 2] = __builtin_amdgcn_mfma_i32_16x16x64_i8(arA[m], b1[n], acc[m][n + 2], 0, 0, 0);
            __builtin_amdgcn_s_setprio(0);
            barrier_();   // p5 trailing barrier: licenses B(t+2) staging at p6

            // ===== phase C (p2/p6): read arB(kh); [p6: stage Bh0+Bh1(t+2)];
            //       bar; lgkm0; Q11 =====
            #pragma unroll
            for (int m = 0; m < 4; ++m)
                arB[m] = *(const i32x4*)(cb + aoffB + (m + 4) * 2048 + c);
            if (kh == 1 && st) {
                stage_half(Bu + kn2,  sw + 32768);
                stage_half(BuH + kn2, sw + 49152);
            }
            barrier_();
            asm volatile("s_waitcnt lgkmcnt(0)" ::: "memory");
            SB();
            __builtin_amdgcn_s_setprio(1);
            #pragma unroll
            for (int m = 0; m < 4; ++m)
                #pragma unroll
                for (int n = 0; n < 2; ++n)
                    acc[m + 4][n + 2] = __builtin_amdgcn_mfma_i32_16x16x64_i8(arB[m], b1[n], acc[m + 4][n + 2], 0, 0, 0);
            __builtin_amdgcn_s_setprio(0);
            barrier_();   // p6 trailing barrier: licenses A(t+2) staging at p7

            // ===== phase D (p3/p7): [p7: stage Ah0+Ah1(t+2)]; bar; Q10;
            //       [p7: counted vmcnt]; bar =====
            if (kh == 1 && st) {
                stage_half(Au + kn2,  sw);
                stage_half(AuH + kn2, sw + 16384);
            }
            barrier_();
            __builtin_amdgcn_s_setprio(1);
            #pragma unroll
            for (int m = 0; m < 4; ++m)
                #pragma unroll
                for (int n = 0; n < 2; ++n)
                    acc[m + 4][n] = __builtin_amdgcn_mfma_i32_16x16x64_i8(arB[m], b0[n], acc[m + 4][n], 0, 0, 0);
            __builtin_amdgcn_s_setprio(0);
            SB();
            if (kh == 1) {
                if (st) {
                    // queue: [t+1 x8 (old), t+2 x8 (new)] -> retire all of t+1
                    asm volatile("s_waitcnt vmcnt(8)" ::: "memory");
                } else if (t + 1 < NT) {
                    asm volatile("s_waitcnt vmcnt(0)" ::: "memory");   // tail drain
                }
            }
            barrier_();
        }
    }

    // ---- epilogue: 16x16 C/D layout col = lane&15, row = kq*4 + j ----
    const float swv = scale[0];
    const float zpv = zpp[0];
    float bv[4];
    #pragma unroll
    for (int n = 0; n < 4; ++n)
        bv[n] = bias[tileCol + wc * 64 + n * 16 + fr];
    #pragma unroll
    for (int m = 0; m < 8; ++m) {
        #pragma unroll
        for (int j = 0; j < 4; ++j) {
            const int grow = tileRow + wr * 128 + m * 16 + kq * 4 + j;
            const float f1 = rs1[grow] * swv;
            const float f2 = zpv * rs2[grow] * swv;
            float* Crow = C + (size_t)grow * N_DIM + tileCol + wc * 64 + fr;
            #pragma unroll
            for (int n = 0; n < 4; ++n)
                Crow[n * 16] = f1 * (float)acc[m][n][j] - f2 + bv[n];
        }
    }
}

// Fallback (only if ws too small): basic LDS-tiled f32 GEMM.
__global__ void gemm_naive(const float* __restrict__ x, const int* __restrict__ wq,
                           const float* __restrict__ sp, const float* __restrict__ zp,
                           const float* __restrict__ bias, float* __restrict__ out) {
    __shared__ float sX[32][33];
    __shared__ float sW[32][33];
    const float s = sp[0], z = zp[0];
    const int tx = threadIdx.x & 15, ty = threadIdx.x >> 4;
    const int row0 = blockIdx.y * 32, col0 = blockIdx.x * 32;
    float acc[2][2] = {};
    for (int k0 = 0; k0 < K_DIM; k0 += 32) {
        for (int i = threadIdx.x; i < 32 * 32; i += 256) {
            int r = i >> 5, cc2 = i & 31;
            sX[r][cc2] = x[(size_t)(row0 + r) * K_DIM + k0 + cc2];
            sW[r][cc2] = ((float)wq[(size_t)(col0 + r) * K_DIM + k0 + cc2] - z) * s;
        }
        __syncthreads();
        #pragma unroll
        for (int k = 0; k < 32; ++k) {
            float xa0 = sX[ty * 2][k], xa1 = sX[ty * 2 + 1][k];
            float wb0 = sW[tx * 2][k], wb1 = sW[tx * 2 + 1][k];
            acc[0][0] += xa0 * wb0; acc[0][1] += xa0 * wb1;
            acc[1][0] += xa1 * wb0; acc[1][1] += xa1 * wb1;
        }
        __syncthreads();
    }
    #pragma unroll
    for (int i = 0; i < 2; ++i)
        #pragma unroll
        for (int j = 0; j < 2; ++j)
            out[(size_t)(row0 + ty * 2 + i) * N_DIM + (col0 + tx * 2 + j)] =
                acc[i][j] + bias[col0 + tx * 2 + j];
}

extern "C" void kernel_launch(void* const* d_in, const int* in_sizes, int n_in,
                              void* d_out, int out_size, void* d_ws, size_t ws_size,
                              hipStream_t stream) {
    const float* x     = (const float*)d_in[0];
    const int*   wq    = (const int*)d_in[1];
    const float* scale = (const float*)d_in[2];
    const float* zp    = (const float*)d_in[3];
    const float* bias  = (const float*)d_in[4];
    float* out = (float*)d_out;

    // ws layout: xq (32Mi) | wq8 (64Mi) | rs1 | rs2
    const size_t offXq = 0;
    const size_t offWq = (size_t)M_DIM * K_DIM;
    const size_t offR1 = offWq + (size_t)N_DIM * K_DIM;
    const size_t offR2 = offR1 + (size_t)M_DIM * sizeof(float);
    const size_t need  = offR2 + (size_t)M_DIM * sizeof(float);

    if (ws_size >= need) {
        signed char* xq  = (signed char*)d_ws + offXq;
        signed char* wq8 = (signed char*)d_ws + offWq;
        float* rs1 = (float*)((char*)d_ws + offR1);
        float* rs2 = (float*)((char*)d_ws + offR2);
        quant_x_kernel<<<M_DIM, 256, 0, stream>>>(x, xq, rs1, rs2);
        quant_w_kernel<<<4096, 256, 0, stream>>>(wq, wq8, (long long)N_DIM * K_DIM);
        (void)hipFuncSetAttribute((const void*)gemm_i8_kernel,
                                  hipFuncAttributeMaxDynamicSharedMemorySize, 131072);
        gemm_i8_kernel<<<(M_DIM / 256) * (N_DIM / 256), 512, 131072, stream>>>(
            xq, wq8, rs1, rs2, scale, zp, bias, out);
    } else {
        dim3 grid(N_DIM / 32, M_DIM / 32);
        gemm_naive<<<grid, 256, 0, stream>>>(x, wq, scale, zp, bias, out);
    }
}

// Round 15
// 658.998 us; speedup vs baseline: 1.3653x; 1.0346x over previous
//
#include <hip/hip_runtime.h>
#include <hip/hip_bf16.h>
#include <cstdint>

// QuantizedLinear: Y[M,N] = X[M,K] . W^T + bias.  M=8192, N=16384, K=4096.
// INT8 path: W -> i8 exact; X -> per-row absmax i8 + row-sum (exact zp corr).
// GEMM mfma_i32_16x16x64_i8, 256x256 tile, BK=128, 8 waves (2x4), 128KiB LDS
// dbuf.  R15: SINGLE barrier per K-tile (kill the barrier convoy — R9's 4
// barriers/K-tile = 5043 cyc = serial DS+MFMA sum; R14's 16 = 5756).
// Per tile: stage ALL of t+1 into the just-freed buffer (license = entry
// barrier: in program order it follows every wave's reads of that buffer,
// and tile-end vmcnt(0)+barrier makes it visible before t+1's reads);
// then each wave FREE-RUNS {12 ds_read -> lgkm(0)+SB -> 32 MFMA} x 2
// k-halves.  No intra-tile barriers -> waves desync, DS pipe pipelines one
// wave's reads under another's MFMA burst (the overlap all phase-locked
// variants forbade).  vmcnt(0) at tile end is ~free (staging issued a full
// tile earlier).  T2 xor-swizzle (0 conflicts), T5 setprio, XCD swizzle.
// Prepass: quant_x + quant_w fused into one launch.

#define M_DIM 8192
#define N_DIM 16384
#define K_DIM 4096
#define BK    128
#define NT    (K_DIM / BK)   // 32 k-tiles

using i32x4 = __attribute__((ext_vector_type(4))) int;

// ---------------- fused prepass: X -> i8 rowwise; W -> i8 exact ----------------
__global__ __launch_bounds__(256) void prep_kernel(const float* __restrict__ x,
                                                   const int* __restrict__ q,
                                                   signed char* __restrict__ xq,
                                                   signed char* __restrict__ wq8,
                                                   float* __restrict__ rs1,
                                                   float* __restrict__ rs2) {
    const int tid = threadIdx.x;
    if (blockIdx.x < M_DIM) {
        const int row = blockIdx.x;
        const float* xr = x + (size_t)row * K_DIM;
        float4 v[4];
        float amax = 0.f;
        #pragma unroll
        for (int j = 0; j < 4; ++j) {
            v[j] = *(const float4*)(xr + j * 1024 + tid * 4);
            amax = fmaxf(amax, fmaxf(fmaxf(fabsf(v[j].x), fabsf(v[j].y)),
                                     fmaxf(fabsf(v[j].z), fabsf(v[j].w))));
        }
        #pragma unroll
        for (int off = 32; off > 0; off >>= 1)
            amax = fmaxf(amax, __shfl_xor(amax, off));
        __shared__ float smax[4];
        __shared__ int   ssum[4];
        const int wv = tid >> 6, ln = tid & 63;
        if (ln == 0) smax[wv] = amax;
        __syncthreads();
        amax = fmaxf(fmaxf(smax[0], smax[1]), fmaxf(smax[2], smax[3]));
        const float s   = amax * (1.0f / 127.0f);
        const float inv = amax > 0.f ? 127.0f / amax : 0.f;
        int sum = 0;
        #pragma unroll
        for (int j = 0; j < 4; ++j) {
            int q0 = (int)__builtin_rintf(v[j].x * inv);
            int q1 = (int)__builtin_rintf(v[j].y * inv);
            int q2 = (int)__builtin_rintf(v[j].z * inv);
            int q3 = (int)__builtin_rintf(v[j].w * inv);
            sum += q0 + q1 + q2 + q3;
            int packed = (q0 & 255) | ((q1 & 255) << 8) | ((q2 & 255) << 16) | ((q3 & 255) << 24);
            *(int*)(xq + (size_t)row * K_DIM + j * 1024 + tid * 4) = packed;
        }
        #pragma unroll
        for (int off = 32; off > 0; off >>= 1)
            sum += __shfl_xor(sum, off);
        if (ln == 0) ssum[wv] = sum;
        __syncthreads();
        if (tid == 0) {
            int t = ssum[0] + ssum[1] + ssum[2] + ssum[3];
            rs1[row] = s;
            rs2[row] = s * (float)t;
        }
    } else {
        const long long n = (long long)N_DIM * K_DIM;
        long long i = (((long long)(blockIdx.x - M_DIM)) * 256 + tid) * 4;
        const long long stride = (long long)4096 * 256 * 4;
        for (; i < n; i += stride) {
            int4 v = *(const int4*)(q + i);
            int packed = (v.x & 255) | ((v.y & 255) << 8) | ((v.z & 255) << 16) | ((v.w & 255) << 24);
            *(int*)(wq8 + i) = packed;
        }
    }
}

// ---------------- GEMM ----------------
#define SB() __builtin_amdgcn_sched_barrier(0)

__device__ __forceinline__ void barrier_() {
    SB();
    asm volatile("" ::: "memory");
    __builtin_amdgcn_s_barrier();
    asm volatile("" ::: "memory");
    SB();
}

// Stage one 128-row x 128-byte half-tile (16 KiB) with 512 threads:
// 2 gload_lds w16; instr j covers rows j*64 + tid>>3.
// LDS[r][c16] = G[r][c16 ^ (r&7)] via inverse-swizzled global source.
__device__ __forceinline__ void stage_half(const signed char* g0, unsigned char* l0) {
    __builtin_amdgcn_global_load_lds((const __attribute__((address_space(1))) void*)g0,
                                     (__attribute__((address_space(3))) void*)l0, 16, 0, 0);
    __builtin_amdgcn_global_load_lds(
        (const __attribute__((address_space(1))) void*)(g0 + (size_t)64 * K_DIM),
        (__attribute__((address_space(3))) void*)(l0 + 8192), 16, 0, 0);
}

__global__ __launch_bounds__(512, 2) void gemm_i8_kernel(const signed char* __restrict__ A,
                                                         const signed char* __restrict__ B,
                                                         const float* __restrict__ rs1,
                                                         const float* __restrict__ rs2,
                                                         const float* __restrict__ scale,
                                                         const float* __restrict__ zpp,
                                                         const float* __restrict__ bias,
                                                         float* __restrict__ C) {
    extern __shared__ unsigned char smem[];   // 128 KiB: 2 bufs x (A 32K + B 32K)

    const int tid  = threadIdx.x;
    const int wave = tid >> 6;
    const int lane = tid & 63;
    const int fr = lane & 15, kq = lane >> 4;      // 16x16 frag: row/col=fr, k-slot=kq
    const int wr = wave >> 2, wc = wave & 3;       // wave tile 128x64 in 2x4 grid

    // XCD-aware bijective swizzle: nwg = 2048, divisible by 8.
    const int swz = (blockIdx.x & 7) * 256 + (blockIdx.x >> 3);
    const int ntn = N_DIM / 256;
    const int tileRow = (swz / ntn) * 256;
    const int tileCol = (swz % ntn) * 256;

    // ---- staging addressing (bytes) ----
    const size_t goff = (size_t)(tid >> 3) * K_DIM + (((tid & 7) ^ ((tid >> 3) & 7)) * 16);
    const signed char* Au  = A + (size_t)tileRow * K_DIM + goff;
    const signed char* Bu  = B + (size_t)tileCol * K_DIM + goff;
    const signed char* AuH = Au + (size_t)128 * K_DIM;
    const signed char* BuH = Bu + (size_t)128 * K_DIM;

    // ---- read addressing (swizzled), byte offsets ----
    const int aoffB = wr * 16384 + fr * 128;            // + m*2048 + cs[kh]
    const int boffB = 32768 + wc * 8192 + fr * 128;     // + n*2048 + cs[kh]
    int cs[2];
    #pragma unroll
    for (int kh = 0; kh < 2; ++kh)
        cs[kh] = ((kh * 4 + kq) ^ (fr & 7)) * 16;

    i32x4 acc[8][4] = {};

    // ---- prologue: stage t0; vmcnt(0); barrier ----
    {
        unsigned char* w0 = smem + wave * 1024;
        stage_half(Au,  w0);
        stage_half(AuH, w0 + 16384);
        stage_half(Bu,  w0 + 32768);
        stage_half(BuH, w0 + 49152);
    }
    SB();
    asm volatile("s_waitcnt vmcnt(0)" ::: "memory");
    barrier_();

    for (int t = 0; t < NT; ++t) {
        const unsigned char* cb = smem + (t & 1) * 65536;
        unsigned char* ow = smem + ((t + 1) & 1) * 65536 + wave * 1024;  // freed buf
        const int kn1 = (t + 1) * BK;

        // stage ALL of t+1 into the just-freed buffer (entry barrier = license)
        if (t + 1 < NT) {
            stage_half(Au + kn1,  ow);
            stage_half(AuH + kn1, ow + 16384);
            stage_half(Bu + kn1,  ow + 32768);
            stage_half(BuH + kn1, ow + 49152);
        }

        // free-run: per k-half {12 reads -> lgkm(0) -> 32 MFMA}; no barriers
        #pragma unroll
        for (int kh = 0; kh < 2; ++kh) {
            const int c = cs[kh];
            i32x4 a[8], b[4];
            #pragma unroll
            for (int m = 0; m < 8; ++m)
                a[m] = *(const i32x4*)(cb + aoffB + m * 2048 + c);
            #pragma unroll
            for (int n = 0; n < 4; ++n)
                b[n] = *(const i32x4*)(cb + boffB + n * 2048 + c);
            asm volatile("s_waitcnt lgkmcnt(0)" ::: "memory");
            SB();
            __builtin_amdgcn_s_setprio(1);
            #pragma unroll
            for (int m = 0; m < 8; ++m)
                #pragma unroll
                for (int n = 0; n < 4; ++n)
                    acc[m][n] = __builtin_amdgcn_mfma_i32_16x16x64_i8(a[m], b[n], acc[m][n], 0, 0, 0);
            __builtin_amdgcn_s_setprio(0);
        }

        // staging issued a full tile ago -> vmcnt(0) ~free; barrier publishes it
        SB();
        asm volatile("s_waitcnt vmcnt(0)" ::: "memory");
        barrier_();
    }

    // ---- epilogue: 16x16 C/D layout col = lane&15, row = kq*4 + j ----
    const float swv = scale[0];
    const float zpv = zpp[0];
    float bv[4];
    #pragma unroll
    for (int n = 0; n < 4; ++n)
        bv[n] = bias[tileCol + wc * 64 + n * 16 + fr];
    #pragma unroll
    for (int m = 0; m < 8; ++m) {
        #pragma unroll
        for (int j = 0; j < 4; ++j) {
            const int grow = tileRow + wr * 128 + m * 16 + kq * 4 + j;
            const float f1 = rs1[grow] * swv;
            const float f2 = zpv * rs2[grow] * swv;
            float* Crow = C + (size_t)grow * N_DIM + tileCol + wc * 64 + fr;
            #pragma unroll
            for (int n = 0; n < 4; ++n)
                Crow[n * 16] = f1 * (float)acc[m][n][j] - f2 + bv[n];
        }
    }
}

// Fallback (only if ws too small): basic LDS-tiled f32 GEMM.
__global__ void gemm_naive(const float* __restrict__ x, const int* __restrict__ wq,
                           const float* __restrict__ sp, const float* __restrict__ zp,
                           const float* __restrict__ bias, float* __restrict__ out) {
    __shared__ float sX[32][33];
    __shared__ float sW[32][33];
    const float s = sp[0], z = zp[0];
    const int tx = threadIdx.x & 15, ty = threadIdx.x >> 4;
    const int row0 = blockIdx.y * 32, col0 = blockIdx.x * 32;
    float acc[2][2] = {};
    for (int k0 = 0; k0 < K_DIM; k0 += 32) {
        for (int i = threadIdx.x; i < 32 * 32; i += 256) {
            int r = i >> 5, cc2 = i & 31;
            sX[r][cc2] = x[(size_t)(row0 + r) * K_DIM + k0 + cc2];
            sW[r][cc2] = ((float)wq[(size_t)(col0 + r) * K_DIM + k0 + cc2] - z) * s;
        }
        __syncthreads();
        #pragma unroll
        for (int k = 0; k < 32; ++k) {
            float xa0 = sX[ty * 2][k], xa1 = sX[ty * 2 + 1][k];
            float wb0 = sW[tx * 2][k], wb1 = sW[tx * 2 + 1][k];
            acc[0][0] += xa0 * wb0; acc[0][1] += xa0 * wb1;
            acc[1][0] += xa1 * wb0; acc[1][1] += xa1 * wb1;
        }
        __syncthreads();
    }
    #pragma unroll
    for (int i = 0; i < 2; ++i)
        #pragma unroll
        for (int j = 0; j < 2; ++j)
            out[(size_t)(row0 + ty * 2 + i) * N_DIM + (col0 + tx * 2 + j)] =
                acc[i][j] + bias[col0 + tx * 2 + j];
}

extern "C" void kernel_launch(void* const* d_in, const int* in_sizes, int n_in,
                              void* d_out, int out_size, void* d_ws, size_t ws_size,
                              hipStream_t stream) {
    const float* x     = (const float*)d_in[0];
    const int*   wq    = (const int*)d_in[1];
    const float* scale = (const float*)d_in[2];
    const float* zp    = (const float*)d_in[3];
    const float* bias  = (const float*)d_in[4];
    float* out = (float*)d_out;

    // ws layout: xq (32Mi) | wq8 (64Mi) | rs1 | rs2
    const size_t offXq = 0;
    const size_t offWq = (size_t)M_DIM * K_DIM;
    const size_t offR1 = offWq + (size_t)N_DIM * K_DIM;
    const size_t offR2 = offR1 + (size_t)M_DIM * sizeof(float);
    const size_t need  = offR2 + (size_t)M_DIM * sizeof(float);

    if (ws_size >= need) {
        signed char* xq  = (signed char*)d_ws + offXq;
        signed char* wq8 = (signed char*)d_ws + offWq;
        float* rs1 = (float*)((char*)d_ws + offR1);
        float* rs2 = (float*)((char*)d_ws + offR2);
        prep_kernel<<<M_DIM + 4096, 256, 0, stream>>>(x, wq, xq, wq8, rs1, rs2);
        (void)hipFuncSetAttribute((const void*)gemm_i8_kernel,
                                  hipFuncAttributeMaxDynamicSharedMemorySize, 131072);
        gemm_i8_kernel<<<(M_DIM / 256) * (N_DIM / 256), 512, 131072, stream>>>(
            xq, wq8, rs1, rs2, scale, zp, bias, out);
    } else {
        dim3 grid(N_DIM / 32, M_DIM / 32);
        gemm_naive<<<grid, 256, 0, stream>>>(x, wq, scale, zp, bias, out);
    }
}

// Round 17
// 612.374 us; speedup vs baseline: 1.4693x; 1.0761x over previous
//
#include <hip/hip_runtime.h>
#include <hip/hip_bf16.h>
#include <cstdint>

// QuantizedLinear: Y[M,N] = X[M,K] . W^T + bias.  M=8192, N=16384, K=4096.
// INT8 path: W -> i8 exact; X -> per-row absmax i8 + row-sum (exact zp corr).
// GEMM mfma_i32_16x16x64_i8, 256x256 tile, BK=128, 8 waves (2x4), 128KiB LDS
// dbuf, R9-verified 4-phase schedule (best: 538us GEMM, race-free).
// R17 = R16 with the compile fix: nontemporal stores use ext_vector_type
// (clang native vector), not HIP_vector_type float4.
// Diagnosis under test: FETCH=1.08GB vs 96MB ideal (A+B fit L3) -> the 512MB
// C stream evicts the panels; all schedule variants plateau at ~3 TB/s.
// Fix: epilogue transposes acc through a per-wave LDS buffer (no barriers)
// so each lane holds 4 consecutive cols; stores are 256B-contiguous-per-row
// NONTEMPORAL (no L3 allocation, no partial-line amplification).
// T2 xor-swizzle (0 conflicts), T5 setprio, XCD-swizzled grid, fused prepass.

#define M_DIM 8192
#define N_DIM 16384
#define K_DIM 4096
#define BK    128
#define NT    (K_DIM / BK)   // 32 k-tiles

using i32x4 = __attribute__((ext_vector_type(4))) int;
using f32x4 = __attribute__((ext_vector_type(4))) float;

// ---------------- fused prepass: X -> i8 rowwise; W -> i8 exact ----------------
__global__ __launch_bounds__(256) void prep_kernel(const float* __restrict__ x,
                                                   const int* __restrict__ q,
                                                   signed char* __restrict__ xq,
                                                   signed char* __restrict__ wq8,
                                                   float* __restrict__ rs1,
                                                   float* __restrict__ rs2) {
    const int tid = threadIdx.x;
    if (blockIdx.x < M_DIM) {
        const int row = blockIdx.x;
        const float* xr = x + (size_t)row * K_DIM;
        float4 v[4];
        float amax = 0.f;
        #pragma unroll
        for (int j = 0; j < 4; ++j) {
            v[j] = *(const float4*)(xr + j * 1024 + tid * 4);
            amax = fmaxf(amax, fmaxf(fmaxf(fabsf(v[j].x), fabsf(v[j].y)),
                                     fmaxf(fabsf(v[j].z), fabsf(v[j].w))));
        }
        #pragma unroll
        for (int off = 32; off > 0; off >>= 1)
            amax = fmaxf(amax, __shfl_xor(amax, off));
        __shared__ float smax[4];
        __shared__ int   ssum[4];
        const int wv = tid >> 6, ln = tid & 63;
        if (ln == 0) smax[wv] = amax;
        __syncthreads();
        amax = fmaxf(fmaxf(smax[0], smax[1]), fmaxf(smax[2], smax[3]));
        const float s   = amax * (1.0f / 127.0f);
        const float inv = amax > 0.f ? 127.0f / amax : 0.f;
        int sum = 0;
        #pragma unroll
        for (int j = 0; j < 4; ++j) {
            int q0 = (int)__builtin_rintf(v[j].x * inv);
            int q1 = (int)__builtin_rintf(v[j].y * inv);
            int q2 = (int)__builtin_rintf(v[j].z * inv);
            int q3 = (int)__builtin_rintf(v[j].w * inv);
            sum += q0 + q1 + q2 + q3;
            int packed = (q0 & 255) | ((q1 & 255) << 8) | ((q2 & 255) << 16) | ((q3 & 255) << 24);
            *(int*)(xq + (size_t)row * K_DIM + j * 1024 + tid * 4) = packed;
        }
        #pragma unroll
        for (int off = 32; off > 0; off >>= 1)
            sum += __shfl_xor(sum, off);
        if (ln == 0) ssum[wv] = sum;
        __syncthreads();
        if (tid == 0) {
            int t = ssum[0] + ssum[1] + ssum[2] + ssum[3];
            rs1[row] = s;
            rs2[row] = s * (float)t;
        }
    } else {
        const long long n = (long long)N_DIM * K_DIM;
        long long i = (((long long)(blockIdx.x - M_DIM)) * 256 + tid) * 4;
        const long long stride = (long long)4096 * 256 * 4;
        for (; i < n; i += stride) {
            int4 v = *(const int4*)(q + i);
            int packed = (v.x & 255) | ((v.y & 255) << 8) | ((v.z & 255) << 16) | ((v.w & 255) << 24);
            *(int*)(wq8 + i) = packed;
        }
    }
}

// ---------------- GEMM ----------------
#define SB() __builtin_amdgcn_sched_barrier(0)

__device__ __forceinline__ void barrier_() {
    SB();
    asm volatile("" ::: "memory");
    __builtin_amdgcn_s_barrier();
    asm volatile("" ::: "memory");
    SB();
}

// Stage one 128-row x 128-byte half-tile (16 KiB) with 512 threads:
// 2 gload_lds w16; instr j covers rows j*64 + tid>>3.
// LDS[r][c16] = G[r][c16 ^ (r&7)] via inverse-swizzled global source.
__device__ __forceinline__ void stage_half(const signed char* g0, unsigned char* l0) {
    __builtin_amdgcn_global_load_lds((const __attribute__((address_space(1))) void*)g0,
                                     (__attribute__((address_space(3))) void*)l0, 16, 0, 0);
    __builtin_amdgcn_global_load_lds(
        (const __attribute__((address_space(1))) void*)(g0 + (size_t)64 * K_DIM),
        (__attribute__((address_space(3))) void*)(l0 + 8192), 16, 0, 0);
}

__global__ __launch_bounds__(512, 2) void gemm_i8_kernel(const signed char* __restrict__ A,
                                                         const signed char* __restrict__ B,
                                                         const float* __restrict__ rs1,
                                                         const float* __restrict__ rs2,
                                                         const float* __restrict__ scale,
                                                         const float* __restrict__ zpp,
                                                         const float* __restrict__ bias,
                                                         float* __restrict__ C) {
    extern __shared__ unsigned char smem[];   // 128 KiB: 2 bufs x (A 32K + B 32K)

    const int tid  = threadIdx.x;
    const int wave = tid >> 6;
    const int lane = tid & 63;
    const int fr = lane & 15, kq = lane >> 4;      // 16x16 frag: row/col = fr, k-slot = kq
    const int wr = wave >> 2, wc = wave & 3;       // wave tile 128x64 in 2x4 grid

    // XCD-aware bijective swizzle: nwg = 2048, divisible by 8.
    const int swz = (blockIdx.x & 7) * 256 + (blockIdx.x >> 3);
    const int ntn = N_DIM / 256;
    const int tileRow = (swz / ntn) * 256;
    const int tileCol = (swz % ntn) * 256;

    // ---- staging addressing (bytes) ----
    const size_t goff = (size_t)(tid >> 3) * K_DIM + (((tid & 7) ^ ((tid >> 3) & 7)) * 16);
    const signed char* Au  = A + (size_t)tileRow * K_DIM + goff;
    const signed char* Bu  = B + (size_t)tileCol * K_DIM + goff;
    const signed char* AuH = Au + (size_t)128 * K_DIM;
    const signed char* BuH = Bu + (size_t)128 * K_DIM;

    // ---- read addressing (swizzled), byte offsets ----
    const int aoffB = wr * 16384 + fr * 128;            // + m*2048 + cs[ks]
    const int boffB = 32768 + wc * 8192 + fr * 128;     // + n*2048 + cs[ks]
    int cs[2];
    #pragma unroll
    for (int ks = 0; ks < 2; ++ks)
        cs[ks] = ((ks * 4 + kq) ^ (fr & 7)) * 16;

    i32x4 acc[8][4] = {};
    i32x4 arA[4][2], arB[4][2], b0r[2][2], b1r[2][2];

    // ---- prologue: stage t0 (8 halves) + t1 (8 halves); vmcnt(8) -> t0 landed ----
    {
        unsigned char* w0 = smem + wave * 1024;
        unsigned char* w1 = smem + 65536 + wave * 1024;
        stage_half(Au,  w0);                // t0 Ah0
        stage_half(AuH, w0 + 16384);        // t0 Ah1
        stage_half(Bu,  w0 + 32768);        // t0 Bh0
        stage_half(BuH, w0 + 49152);        // t0 Bh1
        stage_half(Bu + BK,  w1 + 32768);   // t1 Bh0
        stage_half(BuH + BK, w1 + 49152);   // t1 Bh1
        stage_half(Au + BK,  w1);           // t1 Ah0
        stage_half(AuH + BK, w1 + 16384);   // t1 Ah1
    }
    SB();
    asm volatile("s_waitcnt vmcnt(8)" ::: "memory");   // tile0 landed
    barrier_();
    // boundary reads for t=0: arA (m0-3) then b0r (n0-1)
    #pragma unroll
    for (int m = 0; m < 4; ++m)
        #pragma unroll
        for (int ks = 0; ks < 2; ++ks)
            arA[m][ks] = *(const i32x4*)(smem + aoffB + m * 2048 + cs[ks]);
    #pragma unroll
    for (int n = 0; n < 2; ++n)
        #pragma unroll
        for (int ks = 0; ks < 2; ++ks)
            b0r[n][ks] = *(const i32x4*)(smem + boffB + n * 2048 + cs[ks]);
    SB();

    for (int t = 0; t < NT; ++t) {
        const unsigned char* sbr = smem + (t & 1) * 65536;
        const unsigned char* nxr = smem + ((t + 1) & 1) * 65536;
        unsigned char* sbw = smem + (t & 1) * 65536 + wave * 1024;   // t+2 staging
        const int kn2 = (t + 2) * BK;

        // ===== P1: issue b1r(t); lgkm(4)[arA,b0r ready]; Q00(arA x b0r); bar =====
        #pragma unroll
        for (int n = 0; n < 2; ++n)
            #pragma unroll
            for (int ks = 0; ks < 2; ++ks)
                b1r[n][ks] = *(const i32x4*)(sbr + boffB + (n + 2) * 2048 + cs[ks]);
        SB();
        asm volatile("s_waitcnt lgkmcnt(4)" ::: "memory");
        SB();
        __builtin_amdgcn_s_setprio(1);
        #pragma unroll
        for (int ks = 0; ks < 2; ++ks)
            #pragma unroll
            for (int m = 0; m < 4; ++m)
                #pragma unroll
                for (int n = 0; n < 2; ++n)
                    acc[m][n] = __builtin_amdgcn_mfma_i32_16x16x64_i8(arA[m][ks], b0r[n][ks], acc[m][n], 0, 0, 0);
        __builtin_amdgcn_s_setprio(0);
        barrier_();

        // ===== P2: issue arB(t); lgkm(8)[b1r ready]; Q01(arA x b1r); bar =====
        #pragma unroll
        for (int m = 0; m < 4; ++m)
            #pragma unroll
            for (int ks = 0; ks < 2; ++ks)
                arB[m][ks] = *(const i32x4*)(sbr + aoffB + (m + 4) * 2048 + cs[ks]);
        SB();
        asm volatile("s_waitcnt lgkmcnt(8)" ::: "memory");
        SB();
        __builtin_amdgcn_s_setprio(1);
        #pragma unroll
        for (int ks = 0; ks < 2; ++ks)
            #pragma unroll
            for (int m = 0; m < 4; ++m)
                #pragma unroll
                for (int n = 0; n < 2; ++n)
                    acc[m][n + 2] = __builtin_amdgcn_mfma_i32_16x16x64_i8(arA[m][ks], b1r[n][ks], acc[m][n + 2], 0, 0, 0);
        __builtin_amdgcn_s_setprio(0);
        barrier_();

        // ===== P3: stage Bh0+Bh1(t+2) [licensed]; lgkm(0)[arB ready]; Q11;
        //           counted vmcnt(4); bar =====
        if (t + 2 < NT) {
            stage_half(Bu + kn2,  sbw + 32768);
            stage_half(BuH + kn2, sbw + 49152);
        }
        SB();
        asm volatile("s_waitcnt lgkmcnt(0)" ::: "memory");
        SB();
        __builtin_amdgcn_s_setprio(1);
        #pragma unroll
        for (int ks = 0; ks < 2; ++ks)
            #pragma unroll
            for (int m = 0; m < 4; ++m)
                #pragma unroll
                for (int n = 0; n < 2; ++n)
                    acc[m + 4][n + 2] = __builtin_amdgcn_mfma_i32_16x16x64_i8(arB[m][ks], b1r[n][ks], acc[m + 4][n + 2], 0, 0, 0);
        __builtin_amdgcn_s_setprio(0);
        SB();
        if (t + 2 < NT) {
            asm volatile("s_waitcnt vmcnt(4)" ::: "memory");   // tile t+1 fully landed
        } else {
            asm volatile("s_waitcnt vmcnt(0)" ::: "memory");   // tail drain
        }
        barrier_();

        // ===== P4: read arA(t+1); stage Ah0+Ah1(t+2) [licensed]; Q10; read b0r(t+1) =====
        if (t + 1 < NT) {
            #pragma unroll
            for (int m = 0; m < 4; ++m)
                #pragma unroll
                for (int ks = 0; ks < 2; ++ks)
                    arA[m][ks] = *(const i32x4*)(nxr + aoffB + m * 2048 + cs[ks]);
        }
        if (t + 2 < NT) {
            stage_half(Au + kn2,  sbw);
            stage_half(AuH + kn2, sbw + 16384);
        }
        SB();
        __builtin_amdgcn_s_setprio(1);
        #pragma unroll
        for (int ks = 0; ks < 2; ++ks)
            #pragma unroll
            for (int m = 0; m < 4; ++m)
                #pragma unroll
                for (int n = 0; n < 2; ++n)
                    acc[m + 4][n] = __builtin_amdgcn_mfma_i32_16x16x64_i8(arB[m][ks], b0r[n][ks], acc[m + 4][n], 0, 0, 0);
        __builtin_amdgcn_s_setprio(0);
        SB();
        if (t + 1 < NT) {   // WAR-safe: after Q10 consumed b0r
            #pragma unroll
            for (int n = 0; n < 2; ++n)
                #pragma unroll
                for (int ks = 0; ks < 2; ++ks)
                    b0r[n][ks] = *(const i32x4*)(nxr + boffB + n * 2048 + cs[ks]);
        }
        SB();
        barrier_();
    }

    // ---- epilogue: transpose through per-wave LDS, nontemporal f32x4 stores ----
    // acc layout: row = kq*4+j (within 16), col = fr (within 16).
    // trbuf row stride 68 floats (272B, 16B-aligned); per wave 16x68 f32 = 4352B.
    float* tr = (float*)smem + wave * (16 * 68);
    const float swv = scale[0];
    const float zpv = zpp[0];
    #pragma unroll
    for (int m = 0; m < 8; ++m) {
        // write phase: row-scaled values into trbuf
        #pragma unroll
        for (int j = 0; j < 4; ++j) {
            const int lrow = kq * 4 + j;
            const int grow = tileRow + wr * 128 + m * 16 + lrow;
            const float f1 = rs1[grow] * swv;
            const float f2 = zpv * rs2[grow] * swv;
            #pragma unroll
            for (int n = 0; n < 4; ++n)
                tr[lrow * 68 + n * 16 + fr] = f1 * (float)acc[m][n][j] - f2;
        }
        asm volatile("s_waitcnt lgkmcnt(0)" ::: "memory");
        SB();
        // read phase: lane -> row i*4+(lane>>4), 4 consecutive cols (lane&15)*4
        #pragma unroll
        for (int i = 0; i < 4; ++i) {
            const int lrow = i * 4 + (lane >> 4);
            f32x4 v = *(const f32x4*)(tr + lrow * 68 + (lane & 15) * 4);
            const int grow = tileRow + wr * 128 + m * 16 + lrow;
            const int gcol = tileCol + wc * 64 + (lane & 15) * 4;
            f32x4 bv4 = *(const f32x4*)(bias + gcol);
            v += bv4;
            __builtin_nontemporal_store(v, (f32x4*)(C + (size_t)grow * N_DIM + gcol));
        }
        asm volatile("s_waitcnt lgkmcnt(0)" ::: "memory");   // reads done before next m's writes
        SB();
    }
}

// Fallback (only if ws too small): basic LDS-tiled f32 GEMM.
__global__ void gemm_naive(const float* __restrict__ x, const int* __restrict__ wq,
                           const float* __restrict__ sp, const float* __restrict__ zp,
                           const float* __restrict__ bias, float* __restrict__ out) {
    __shared__ float sX[32][33];
    __shared__ float sW[32][33];
    const float s = sp[0], z = zp[0];
    const int tx = threadIdx.x & 15, ty = threadIdx.x >> 4;
    const int row0 = blockIdx.y * 32, col0 = blockIdx.x * 32;
    float acc[2][2] = {};
    for (int k0 = 0; k0 < K_DIM; k0 += 32) {
        for (int i = threadIdx.x; i < 32 * 32; i += 256) {
            int r = i >> 5, cc2 = i & 31;
            sX[r][cc2] = x[(size_t)(row0 + r) * K_DIM + k0 + cc2];
            sW[r][cc2] = ((float)wq[(size_t)(col0 + r) * K_DIM + k0 + cc2] - z) * s;
        }
        __syncthreads();
        #pragma unroll
        for (int k = 0; k < 32; ++k) {
            float xa0 = sX[ty * 2][k], xa1 = sX[ty * 2 + 1][k];
            float wb0 = sW[tx * 2][k], wb1 = sW[tx * 2 + 1][k];
            acc[0][0] += xa0 * wb0; acc[0][1] += xa0 * wb1;
            acc[1][0] += xa1 * wb0; acc[1][1] += xa1 * wb1;
        }
        __syncthreads();
    }
    #pragma unroll
    for (int i = 0; i < 2; ++i)
        #pragma unroll
        for (int j = 0; j < 2; ++j)
            out[(size_t)(row0 + ty * 2 + i) * N_DIM + (col0 + tx * 2 + j)] =
                acc[i][j] + bias[col0 + tx * 2 + j];
}

extern "C" void kernel_launch(void* const* d_in, const int* in_sizes, int n_in,
                              void* d_out, int out_size, void* d_ws, size_t ws_size,
                              hipStream_t stream) {
    const float* x     = (const float*)d_in[0];
    const int*   wq    = (const int*)d_in[1];
    const float* scale = (const float*)d_in[2];
    const float* zp    = (const float*)d_in[3];
    const float* bias  = (const float*)d_in[4];
    float* out = (float*)d_out;

    // ws layout: xq (32Mi) | wq8 (64Mi) | rs1 | rs2
    const size_t offXq = 0;
    const size_t offWq = (size_t)M_DIM * K_DIM;
    const size_t offR1 = offWq + (size_t)N_DIM * K_DIM;
    const size_t offR2 = offR1 + (size_t)M_DIM * sizeof(float);
    const size_t need  = offR2 + (size_t)M_DIM * sizeof(float);

    if (ws_size >= need) {
        signed char* xq  = (signed char*)d_ws + offXq;
        signed char* wq8 = (signed char*)d_ws + offWq;
        float* rs1 = (float*)((char*)d_ws + offR1);
        float* rs2 = (float*)((char*)d_ws + offR2);
        prep_kernel<<<M_DIM + 4096, 256, 0, stream>>>(x, wq, xq, wq8, rs1, rs2);
        (void)hipFuncSetAttribute((const void*)gemm_i8_kernel,
                                  hipFuncAttributeMaxDynamicSharedMemorySize, 131072);
        gemm_i8_kernel<<<(M_DIM / 256) * (N_DIM / 256), 512, 131072, stream>>>(
            xq, wq8, rs1, rs2, scale, zp, bias, out);
    } else {
        dim3 grid(N_DIM / 32, M_DIM / 32);
        gemm_naive<<<grid, 256, 0, stream>>>(x, wq, scale, zp, bias, out);
    }
}